// Round 1
// baseline (319.254 us; speedup 1.0000x reference)
//
#include <hip/hip_runtime.h>
#include <math.h>

#define Bn 8
#define Cn 128
#define Nn 4096   // H*W
#define Mn 1024   // N/4
#define C8n 16
#define C2n 64

// ---------------------------------------------------------------------------
// K1: conv1x1 (+bias) then 2x2 maxpool for phi [C8] and g [C2].
// Outputs TRANSPOSED: phi_t[b][m][d], g_t[b][m][c]  (m-major for LDS staging).
// One block per (b, h2): stages the two source rows of x for all 128 channels
// into LDS (64 KB), then computes 80 output channels x 32 pooled columns.
// ---------------------------------------------------------------------------
__global__ __launch_bounds__(256) void k1_convpool(
    const float* __restrict__ x,
    const float* __restrict__ w_phi, const float* __restrict__ b_phi,
    const float* __restrict__ w_g,   const float* __restrict__ b_g,
    float* __restrict__ phi_t, float* __restrict__ g_t)
{
    __shared__ float xs[Cn][128];   // 64 KB: [channel][2 rows * 64 cols]
    const int bx  = blockIdx.x;
    const int b   = bx >> 5;
    const int h2  = bx & 31;
    const int tid = threadIdx.x;

    // stage: rows 2*h2, 2*h2+1 are 128 contiguous floats per channel
    const float* xb = x + (size_t)b * Cn * Nn + h2 * 128;
    #pragma unroll
    for (int i = 0; i < 16; ++i) {
        int f4 = tid + i * 256;          // 4096 float4 total
        int c  = f4 >> 5;                // 32 float4 per channel
        int p4 = f4 & 31;
        float4 v = *(const float4*)(xb + (size_t)c * Nn + p4 * 4);
        *(float4*)(&xs[c][p4 * 4]) = v;
    }
    __syncthreads();

    // 80 oc x 32 w2 = 2560 outputs, 10 per thread
    #pragma unroll
    for (int k = 0; k < 10; ++k) {
        int oi = tid + k * 256;
        int w2 = oi & 31;
        int oc = oi >> 5;                // 0..79 (0..15 phi, 16..79 g)
        const float* wrow;
        float bias;
        if (oc < C8n) { wrow = w_phi + oc * Cn;          bias = b_phi[oc]; }
        else          { wrow = w_g + (oc - C8n) * Cn;    bias = b_g[oc - C8n]; }
        float a0 = 0.f, a1 = 0.f, a2 = 0.f, a3 = 0.f;
        const int p = 2 * w2;
        for (int c = 0; c < Cn; ++c) {
            float wv = wrow[c];
            a0 = fmaf(wv, xs[c][p],      a0);
            a1 = fmaf(wv, xs[c][p + 1],  a1);
            a2 = fmaf(wv, xs[c][p + 64], a2);
            a3 = fmaf(wv, xs[c][p + 65], a3);
        }
        float r = fmaxf(fmaxf(a0, a1), fmaxf(a2, a3)) + bias;
        int m = h2 * 32 + w2;
        if (oc < C8n) phi_t[((size_t)b * Mn + m) * C8n + oc]        = r;
        else          g_t [((size_t)b * Mn + m) * C2n + (oc - C8n)] = r;
    }
}

// ---------------------------------------------------------------------------
// K2: fused theta-conv + flash softmax(theta^T phi) + (g @ attn^T) + final
// conv1x1(w_attn) + residual. One thread owns one n; the m-range is split in
// half across lane pairs (lane ^ 32) and merged with shuffles at the end.
// Block = 256 threads covers 128 n. Grid = 8 b * 32 tiles = 256 blocks.
// LDS: 40 KB = phi chunk [128][16] (8 KB) + g chunk [128][64] (32 KB);
// the epilogue reuses the buffer for w_attn [128][64] (32 KB).
// ---------------------------------------------------------------------------
__global__ __launch_bounds__(256) void k2_attn(
    const float* __restrict__ x,
    const float* __restrict__ w_theta, const float* __restrict__ b_theta,
    const float* __restrict__ phi_t,   const float* __restrict__ g_t,
    const float* __restrict__ w_attn,  const float* __restrict__ b_attn,
    const float* __restrict__ sigma_p,
    float* __restrict__ out)
{
    __shared__ float smem[10240];        // 40 KB
    float* phis = smem;                  // [128][16]
    float* gs   = smem + 2048;           // [128][64]

    const int bx   = blockIdx.x;
    const int b    = bx >> 5;
    const int n0   = (bx & 31) * 128;
    const int tid  = threadIdx.x;
    const int lane = tid & 63;
    const int wave = tid >> 6;
    const int mh   = (lane >> 5);        // 0/1 -> which m-half this lane does
    const int n    = n0 + wave * 32 + (lane & 31);

    // ---- theta[:, n] (conv1x1 with bias), both halves compute the same ----
    float th[C8n];
    #pragma unroll
    for (int d = 0; d < C8n; ++d) th[d] = b_theta[d];
    {
        const float* xcol = x + (size_t)b * Cn * Nn + n;
        for (int c = 0; c < Cn; ++c) {
            float xv = xcol[(size_t)c * Nn];
            #pragma unroll
            for (int d = 0; d < C8n; ++d)
                th[d] = fmaf(w_theta[d * Cn + c], xv, th[d]);
        }
    }

    // ---- flash loop over m (this lane does 512 of the 1024 m's) ----
    float acc[C2n];
    #pragma unroll
    for (int c = 0; c < C2n; ++c) acc[c] = 0.f;
    float rmax = -INFINITY, L = 0.f;

    const float* phib = phi_t + (size_t)b * Mn * C8n;
    const float* gb   = g_t   + (size_t)b * Mn * C2n;

    for (int mc = 0; mc < Mn; mc += 128) {
        __syncthreads();
        {   // stage phi chunk: 512 float4
            const float4* src = (const float4*)(phib + (size_t)mc * C8n);
            float4* dst = (float4*)phis;
            dst[tid]       = src[tid];
            dst[tid + 256] = src[tid + 256];
            // stage g chunk: 2048 float4
            const float4* gsrc = (const float4*)(gb + (size_t)mc * C2n);
            float4* gdst = (float4*)gs;
            #pragma unroll
            for (int i = 0; i < 8; ++i) gdst[tid + i * 256] = gsrc[tid + i * 256];
        }
        __syncthreads();

        for (int j = 0; j < 64; ++j) {
            const int mm = mh * 64 + j;
            const float* ph = phis + mm * C8n;
            float s = 0.f;
            #pragma unroll
            for (int d = 0; d < C8n; ++d) s = fmaf(th[d], ph[d], s);
            if (s > rmax) {              // rare (~log M per thread)
                float sc = __expf(rmax - s);
                rmax = s;
                L *= sc;
                #pragma unroll
                for (int c = 0; c < C2n; ++c) acc[c] *= sc;
            }
            float p = __expf(s - rmax);
            L += p;
            const float* gr = gs + mm * C2n;
            #pragma unroll
            for (int c = 0; c < C2n; ++c) acc[c] = fmaf(p, gr[c], acc[c]);
        }
    }

    // ---- merge the two m-halves (partner = lane ^ 32) ----
    float omax = __shfl_xor(rmax, 32, 64);
    float nmax = fmaxf(rmax, omax);
    float sc   = __expf(rmax - nmax);
    float Ls   = L * sc;
    L = Ls + __shfl_xor(Ls, 32, 64);
    float inv = 1.f / L;
    #pragma unroll
    for (int c = 0; c < C2n; ++c) {
        float a = acc[c] * sc;
        a += __shfl_xor(a, 32, 64);
        acc[c] = a * inv;                // normalized attn_g[c][n]
    }

    // ---- epilogue: out[o][n] = x[o][n] + sigma*(b_attn[o] + w_attn[o,:]·acc) ----
    __syncthreads();
    {   // stage w_attn [128][64] = 2048 float4
        const float4* src = (const float4*)w_attn;
        float4* dst = (float4*)smem;
        #pragma unroll
        for (int i = 0; i < 8; ++i) dst[tid + i * 256] = src[tid + i * 256];
    }
    __syncthreads();

    const float sigma = sigma_p[0];
    const int obase = mh * 64;           // lane-half splits the 128 outputs
    const float* xcol = x   + (size_t)b * Cn * Nn + n;
    float*       ocol = out + (size_t)b * Cn * Nn + n;
    for (int k = 0; k < 64; ++k) {
        int o = obase + k;
        const float* wr = smem + o * C2n;
        float v = 0.f;
        #pragma unroll
        for (int c = 0; c < C2n; ++c) v = fmaf(wr[c], acc[c], v);
        v += b_attn[o];
        ocol[(size_t)o * Nn] = xcol[(size_t)o * Nn] + sigma * v;
    }
}

extern "C" void kernel_launch(void* const* d_in, const int* in_sizes, int n_in,
                              void* d_out, int out_size, void* d_ws, size_t ws_size,
                              hipStream_t stream) {
    const float* x       = (const float*)d_in[0];
    const float* w_theta = (const float*)d_in[1];
    const float* b_theta = (const float*)d_in[2];
    const float* w_phi   = (const float*)d_in[3];
    const float* b_phi   = (const float*)d_in[4];
    const float* w_g     = (const float*)d_in[5];
    const float* b_g     = (const float*)d_in[6];
    const float* w_attn  = (const float*)d_in[7];
    const float* b_attn  = (const float*)d_in[8];
    const float* sigma   = (const float*)d_in[9];
    float* out = (float*)d_out;

    // workspace: phi_t [8][1024][16] (512 KB) then g_t [8][1024][64] (2 MB)
    float* phi_t = (float*)d_ws;
    float* g_t   = (float*)((char*)d_ws + (size_t)Bn * Mn * C8n * sizeof(float));

    k1_convpool<<<Bn * 32, 256, 0, stream>>>(x, w_phi, b_phi, w_g, b_g, phi_t, g_t);
    k2_attn<<<Bn * 32, 256, 0, stream>>>(x, w_theta, b_theta, phi_t, g_t,
                                         w_attn, b_attn, sigma, out);
}

// Round 2
// 248.469 us; speedup vs baseline: 1.2849x; 1.2849x over previous
//
#include <hip/hip_runtime.h>
#include <math.h>

#define Bn 8
#define Cn 128
#define Nn 4096   // H*W
#define Mn 1024   // N/4
#define C8n 16
#define C2n 64

// ---------------------------------------------------------------------------
// K1: conv1x1 (+bias) then 2x2 maxpool for phi [C8] and g [C2].
// Outputs TRANSPOSED: phi_t[b][m][d], g_t[b][m][c]  (m-major for k2 staging).
// Grid 512 = 8 b * 32 h2-rows * 2 oc-halves. Each block stages the two source
// rows of x in 64-channel chunks (32 KB LDS) and computes 40 oc x 32 w2.
// ---------------------------------------------------------------------------
__global__ __launch_bounds__(256) void k1_convpool(
    const float* __restrict__ x,
    const float* __restrict__ w_phi, const float* __restrict__ b_phi,
    const float* __restrict__ w_g,   const float* __restrict__ b_g,
    float* __restrict__ phi_t, float* __restrict__ g_t)
{
    __shared__ float xs[64][128];        // 32 KB: [channel chunk][2 rows * 64 cols]
    const int bx   = blockIdx.x;
    const int b    = bx >> 6;
    const int h2   = (bx >> 1) & 31;
    const int half = bx & 1;             // 0: oc 0..39, 1: oc 40..79
    const int tid  = threadIdx.x;
    const int w2   = tid & 31;
    const int ocb  = tid >> 5;           // 0..7
    const int p    = 2 * w2;

    float a[5][4];
    #pragma unroll
    for (int k = 0; k < 5; ++k)
        { a[k][0]=0.f; a[k][1]=0.f; a[k][2]=0.f; a[k][3]=0.f; }

    const float* xb = x + (size_t)b * Cn * Nn + h2 * 128;

    for (int c0 = 0; c0 < Cn; c0 += 64) {
        __syncthreads();
        #pragma unroll
        for (int i = 0; i < 8; ++i) {            // 2048 float4 stage
            int f4 = tid + i * 256;
            int c  = f4 >> 5;
            int p4 = f4 & 31;
            *(float4*)&xs[c][p4 * 4] =
                *(const float4*)(xb + (size_t)(c0 + c) * Nn + p4 * 4);
        }
        __syncthreads();

        #pragma unroll
        for (int k = 0; k < 5; ++k) {
            const int oc = half * 40 + ocb + k * 8;
            const float* wrow = (oc < C8n) ? (w_phi + oc * Cn + c0)
                                           : (w_g + (oc - C8n) * Cn + c0);
            for (int c = 0; c < 64; c += 4) {
                float4 wv = *(const float4*)(wrow + c);
                #pragma unroll
                for (int q = 0; q < 4; ++q) {
                    float w = (q == 0) ? wv.x : (q == 1) ? wv.y : (q == 2) ? wv.z : wv.w;
                    float2 v01 = *(const float2*)&xs[c + q][p];
                    float2 v23 = *(const float2*)&xs[c + q][p + 64];
                    a[k][0] = fmaf(w, v01.x, a[k][0]);
                    a[k][1] = fmaf(w, v01.y, a[k][1]);
                    a[k][2] = fmaf(w, v23.x, a[k][2]);
                    a[k][3] = fmaf(w, v23.y, a[k][3]);
                }
            }
        }
    }

    const int m = h2 * 32 + w2;
    #pragma unroll
    for (int k = 0; k < 5; ++k) {
        const int oc = half * 40 + ocb + k * 8;
        float bias = (oc < C8n) ? b_phi[oc] : b_g[oc - C8n];
        float r = fmaxf(fmaxf(a[k][0], a[k][1]), fmaxf(a[k][2], a[k][3])) + bias;
        if (oc < C8n) phi_t[((size_t)b * Mn + m) * C8n + oc]        = r;
        else          g_t [((size_t)b * Mn + m) * C2n + (oc - C8n)] = r;
    }
}

// ---------------------------------------------------------------------------
// K2: fused theta-conv + flash softmax(theta^T phi) + (g @ attn^T) + final
// conv1x1(w_attn) + residual.
// Grid 1024 = 8 b * 128 n-tiles of 32. Each thread owns one n and 1/8 of the
// m-range (mg = lane>>3); partial softmax states merge via shfl_xor 8/16/32.
// m staged in 64-chunks; per 8-m sub-chunk: scores to regs, ONE unconditional
// rescale (no divergent branch), then exp + rank-1 acc updates (float4 LDS).
// LDS rows padded (phi 16->20, g/w_attn 64->68) and m interleaved as j*8+mg
// so the 8 concurrent row reads hit distinct bank quads.
// ---------------------------------------------------------------------------
__global__ __launch_bounds__(256, 4) void k2_attn(
    const float* __restrict__ x,
    const float* __restrict__ w_theta, const float* __restrict__ b_theta,
    const float* __restrict__ phi_t,   const float* __restrict__ g_t,
    const float* __restrict__ w_attn,  const float* __restrict__ b_attn,
    const float* __restrict__ sigma_p,
    float* __restrict__ out)
{
    __shared__ float smem[8704];         // 34 KB; epilogue reuses all of it
    float* phis = smem;                  // [64][20] padded
    float* gs   = smem + 1280;           // [64][68] padded

    const int bx   = blockIdx.x;
    const int b    = bx >> 7;
    const int n0   = (bx & 127) * 32;
    const int tid  = threadIdx.x;
    const int lane = tid & 63;
    const int wave = tid >> 6;
    const int mg   = lane >> 3;          // 0..7: which m-eighth
    const int nl   = lane & 7;
    const int n    = n0 + wave * 8 + nl;

    // ---- theta[:, n] (conv1x1 + bias); w_theta loads are lane-uniform -> s_load
    float th[C8n];
    #pragma unroll
    for (int d = 0; d < C8n; ++d) th[d] = b_theta[d];
    {
        const float* xcol = x + (size_t)b * Cn * Nn + n;
        for (int c = 0; c < Cn; ++c) {
            float xv = xcol[(size_t)c * Nn];
            #pragma unroll
            for (int d = 0; d < C8n; ++d)
                th[d] = fmaf(w_theta[d * Cn + c], xv, th[d]);
        }
    }

    float acc[C2n];
    #pragma unroll
    for (int c = 0; c < C2n; ++c) acc[c] = 0.f;
    float rmax = -INFINITY, L = 0.f;

    const float* phib = phi_t + (size_t)b * Mn * C8n;
    const float* gb   = g_t   + (size_t)b * Mn * C2n;

    for (int mc = 0; mc < Mn; mc += 64) {
        __syncthreads();
        {   // stage phi chunk (256 f4) and g chunk (1024 f4), padded rows
            const float4* ps = (const float4*)(phib + (size_t)mc * C8n);
            int pm = tid >> 2, pd = tid & 3;
            *(float4*)(phis + pm * 20 + pd * 4) = ps[tid];
            const float4* gsrc = (const float4*)(gb + (size_t)mc * C2n);
            #pragma unroll
            for (int r = 0; r < 4; ++r) {
                int i  = tid + r * 256;
                int gm = i >> 4, gc = i & 15;
                *(float4*)(gs + gm * 68 + gc * 4) = gsrc[i];
            }
        }
        __syncthreads();

        // scores for this thread's 8 m's
        float sv[8];
        #pragma unroll
        for (int j = 0; j < 8; ++j) {
            const float* ph = phis + (j * 8 + mg) * 20;
            float4 p0 = *(const float4*)(ph);
            float4 p1 = *(const float4*)(ph + 4);
            float4 p2 = *(const float4*)(ph + 8);
            float4 p3 = *(const float4*)(ph + 12);
            float s;
            s = th[0] * p0.x;
            s = fmaf(th[1],  p0.y, s); s = fmaf(th[2],  p0.z, s); s = fmaf(th[3],  p0.w, s);
            s = fmaf(th[4],  p1.x, s); s = fmaf(th[5],  p1.y, s); s = fmaf(th[6],  p1.z, s);
            s = fmaf(th[7],  p1.w, s); s = fmaf(th[8],  p2.x, s); s = fmaf(th[9],  p2.y, s);
            s = fmaf(th[10], p2.z, s); s = fmaf(th[11], p2.w, s); s = fmaf(th[12], p3.x, s);
            s = fmaf(th[13], p3.y, s); s = fmaf(th[14], p3.z, s); s = fmaf(th[15], p3.w, s);
            sv[j] = s;
        }
        // one unconditional rescale per 8-m chunk
        float cmax = sv[0];
        #pragma unroll
        for (int j = 1; j < 8; ++j) cmax = fmaxf(cmax, sv[j]);
        float nmax = fmaxf(rmax, cmax);
        float sc = __expf(rmax - nmax);   // exp(-inf)=0 handles first chunk
        rmax = nmax;
        L *= sc;
        #pragma unroll
        for (int c = 0; c < C2n; ++c) acc[c] *= sc;

        #pragma unroll
        for (int j = 0; j < 8; ++j) {
            float pj = __expf(sv[j] - rmax);
            L += pj;
            const float* gr = gs + (j * 8 + mg) * 68;
            #pragma unroll
            for (int c4 = 0; c4 < 16; ++c4) {
                float4 gv = *(const float4*)(gr + c4 * 4);
                acc[c4 * 4 + 0] = fmaf(pj, gv.x, acc[c4 * 4 + 0]);
                acc[c4 * 4 + 1] = fmaf(pj, gv.y, acc[c4 * 4 + 1]);
                acc[c4 * 4 + 2] = fmaf(pj, gv.z, acc[c4 * 4 + 2]);
                acc[c4 * 4 + 3] = fmaf(pj, gv.w, acc[c4 * 4 + 3]);
            }
        }
    }

    // ---- merge the 8 m-partitions (xor distances 8, 16, 32) ----
    float gmax = rmax;
    gmax = fmaxf(gmax, __shfl_xor(gmax, 8,  64));
    gmax = fmaxf(gmax, __shfl_xor(gmax, 16, 64));
    gmax = fmaxf(gmax, __shfl_xor(gmax, 32, 64));
    float msc = __expf(rmax - gmax);
    float Ls  = L * msc;
    Ls += __shfl_xor(Ls, 8,  64);
    Ls += __shfl_xor(Ls, 16, 64);
    Ls += __shfl_xor(Ls, 32, 64);
    float inv = 1.f / Ls;
    #pragma unroll
    for (int c = 0; c < C2n; ++c) {
        float a = acc[c] * msc;
        a += __shfl_xor(a, 8,  64);
        a += __shfl_xor(a, 16, 64);
        a += __shfl_xor(a, 32, 64);
        acc[c] = a * inv;                // normalized attn_g[c][n], in all 8 copies
    }

    // ---- epilogue: out[o][n] = x[o][n] + sigma*(b_attn[o] + w_attn[o,:]·acc)
    __syncthreads();
    {   // stage w_attn padded [128][68]
        const float4* src = (const float4*)w_attn;
        #pragma unroll
        for (int r = 0; r < 8; ++r) {
            int i  = tid + r * 256;
            int o  = i >> 4, c4 = i & 15;
            *(float4*)(smem + o * 68 + c4 * 4) = src[i];
        }
    }
    __syncthreads();

    const float sigma = sigma_p[0];
    const float* xcol = x   + (size_t)b * Cn * Nn + n;
    float*       ocol = out + (size_t)b * Cn * Nn + n;
    #pragma unroll
    for (int k = 0; k < 16; ++k) {
        const int o = k * 8 + mg;        // mg-interleaved rows: distinct bank quads
        const float* wr = smem + o * 68;
        float v = 0.f;
        #pragma unroll
        for (int c4 = 0; c4 < 16; ++c4) {
            float4 wv = *(const float4*)(wr + c4 * 4);
            v = fmaf(wv.x, acc[c4 * 4 + 0], v);
            v = fmaf(wv.y, acc[c4 * 4 + 1], v);
            v = fmaf(wv.z, acc[c4 * 4 + 2], v);
            v = fmaf(wv.w, acc[c4 * 4 + 3], v);
        }
        v += b_attn[o];
        ocol[(size_t)o * Nn] = xcol[(size_t)o * Nn] + sigma * v;
    }
}

extern "C" void kernel_launch(void* const* d_in, const int* in_sizes, int n_in,
                              void* d_out, int out_size, void* d_ws, size_t ws_size,
                              hipStream_t stream) {
    const float* x       = (const float*)d_in[0];
    const float* w_theta = (const float*)d_in[1];
    const float* b_theta = (const float*)d_in[2];
    const float* w_phi   = (const float*)d_in[3];
    const float* b_phi   = (const float*)d_in[4];
    const float* w_g     = (const float*)d_in[5];
    const float* b_g     = (const float*)d_in[6];
    const float* w_attn  = (const float*)d_in[7];
    const float* b_attn  = (const float*)d_in[8];
    const float* sigma   = (const float*)d_in[9];
    float* out = (float*)d_out;

    float* phi_t = (float*)d_ws;                                         // [8][1024][16]
    float* g_t   = (float*)((char*)d_ws + (size_t)Bn * Mn * C8n * 4);    // [8][1024][64]

    k1_convpool<<<Bn * 64, 256, 0, stream>>>(x, w_phi, b_phi, w_g, b_g, phi_t, g_t);
    k2_attn<<<Bn * 128, 256, 0, stream>>>(x, w_theta, b_theta, phi_t, g_t,
                                          w_attn, b_attn, sigma, out);
}

// Round 3
// 121.046 us; speedup vs baseline: 2.6375x; 2.0527x over previous
//
#include <hip/hip_runtime.h>
#include <math.h>

#define Bn 8
#define Cn 128
#define Nn 4096   // H*W
#define Mn 1024   // N/4
#define C8n 16
#define C2n 64

typedef __attribute__((ext_vector_type(8))) short short8;   // 8 bf16 = 4 VGPRs
typedef __attribute__((ext_vector_type(4))) float floatx4;  // MFMA C/D

__device__ __forceinline__ unsigned short f2bf(float f) {
    union { float f; unsigned u; } v; v.f = f;
    unsigned r = v.u + 0x7fff + ((v.u >> 16) & 1);   // RNE
    return (unsigned short)(r >> 16);
}

// ---------------------------------------------------------------------------
// K1: preprocess. Per block (b, h2): stage x rows 2h2,2h2+1 (all 128 c) + all
// weights in LDS. Waves 0-9: conv+maxpool for phi/g. Waves 10-15: theta.
// Outputs (bf16, ws):
//  thA[b][nt 256][qd 2][nl 16][dj 8]  — theta*log2e in MFMA A-frag order
//  phB[b][mt 64][qd 2][ml 16][dj 8]   — phi in MFMA B-frag order (k=d, zero-padded in k2)
//  gB [b][ch 32][cs 4][mq 4][cl 16][mj 8] — g in B-frag order, m permuted by
//     s = ((m&15)<<1)|(m>>4) within each 32-chunk (matches k2's packed P stores)
// ---------------------------------------------------------------------------
__global__ __launch_bounds__(1024) void k1_pre(
    const float* __restrict__ x,
    const float* __restrict__ w_theta, const float* __restrict__ b_theta,
    const float* __restrict__ w_phi,   const float* __restrict__ b_phi,
    const float* __restrict__ w_g,     const float* __restrict__ b_g,
    unsigned short* __restrict__ thA,
    unsigned short* __restrict__ phB,
    unsigned short* __restrict__ gB)
{
    __shared__ float xs[128][128];   // 64 KB [c][pos], pos = p in [0,128)
    __shared__ float ws[80][128];    // 40 KB w_phi rows 0..15, w_g rows 16..79
    __shared__ float wt[16][128];    // 8 KB  w_theta
    const int bx = blockIdx.x;
    const int b  = bx & 7;           // b = bx&7 -> XCD-local
    const int h2 = bx >> 3;
    const int t  = threadIdx.x;

    // ---- stage x: rows 2h2,2h2+1 are 128 contiguous floats per channel ----
    const float* xb = x + (size_t)b * Cn * Nn + h2 * 128;
    #pragma unroll
    for (int k = 0; k < 4; ++k) {
        int i = t + k * 1024;                 // 4096 float4
        int c = i >> 5, p4 = i & 31;
        *(float4*)&xs[c][p4 * 4] = *(const float4*)(xb + (size_t)c * Nn + p4 * 4);
    }
    #pragma unroll
    for (int k = 0; k < 3; ++k) {
        int i = t + k * 1024;                 // 2560 float4
        if (i < 2560) {
            int r = i >> 5, c4 = i & 31;
            float4 v = (r < C8n) ? *(const float4*)(w_phi + r * Cn + c4 * 4)
                                 : *(const float4*)(w_g + (r - C8n) * Cn + c4 * 4);
            *(float4*)&ws[r][c4 * 4] = v;
        }
    }
    if (t < 512) {
        int r = t >> 5, c4 = t & 31;
        *(float4*)&wt[r][c4 * 4] = *(const float4*)(w_theta + r * Cn + c4 * 4);
    }
    __syncthreads();

    if (t < 640) {
        // ---- phi/g conv + pool: unit = (4 oc, 1 pooled col) ----
        const int oc0 = (t >> 5) * 4;
        const int w2  = t & 31;
        const int p   = 2 * w2;
        float a[4][4];
        #pragma unroll
        for (int q = 0; q < 4; ++q) { a[q][0]=0.f; a[q][1]=0.f; a[q][2]=0.f; a[q][3]=0.f; }
        for (int c = 0; c < 128; c += 4) {
            float2 e[4][2];
            #pragma unroll
            for (int cq = 0; cq < 4; ++cq) {
                e[cq][0] = *(float2*)&xs[c + cq][p];       // pos p, p+1
                e[cq][1] = *(float2*)&xs[c + cq][p + 64];  // pos p+64, p+65
            }
            #pragma unroll
            for (int q = 0; q < 4; ++q) {
                float4 wv = *(float4*)&ws[oc0 + q][c];
                a[q][0] = fmaf(wv.x, e[0][0].x, a[q][0]); a[q][1] = fmaf(wv.x, e[0][0].y, a[q][1]);
                a[q][2] = fmaf(wv.x, e[0][1].x, a[q][2]); a[q][3] = fmaf(wv.x, e[0][1].y, a[q][3]);
                a[q][0] = fmaf(wv.y, e[1][0].x, a[q][0]); a[q][1] = fmaf(wv.y, e[1][0].y, a[q][1]);
                a[q][2] = fmaf(wv.y, e[1][1].x, a[q][2]); a[q][3] = fmaf(wv.y, e[1][1].y, a[q][3]);
                a[q][0] = fmaf(wv.z, e[2][0].x, a[q][0]); a[q][1] = fmaf(wv.z, e[2][0].y, a[q][1]);
                a[q][2] = fmaf(wv.z, e[2][1].x, a[q][2]); a[q][3] = fmaf(wv.z, e[2][1].y, a[q][3]);
                a[q][0] = fmaf(wv.w, e[3][0].x, a[q][0]); a[q][1] = fmaf(wv.w, e[3][0].y, a[q][1]);
                a[q][2] = fmaf(wv.w, e[3][1].x, a[q][2]); a[q][3] = fmaf(wv.w, e[3][1].y, a[q][3]);
            }
        }
        #pragma unroll
        for (int q = 0; q < 4; ++q) {
            const int oc = oc0 + q;
            float bias = (oc < C8n) ? b_phi[oc] : b_g[oc - C8n];
            float r = fmaxf(fmaxf(a[q][0], a[q][1]), fmaxf(a[q][2], a[q][3])) + bias;
            unsigned short hv = f2bf(r);
            if (oc < C8n) {   // phi: d = oc
                int mt = h2 * 2 + (w2 >> 4), ml = w2 & 15;
                phB[(((size_t)b * 64 + mt) * 2 + (oc >> 3)) * 128 + ml * 8 + (oc & 7)] = hv;
            } else {          // g: c = oc-16, permuted position s within 32-chunk
                int c = oc - C8n;
                int s = ((w2 & 15) << 1) | (w2 >> 4);
                gB[((((size_t)b * 32 + h2) * 4 + (c >> 4)) * 4 + (s >> 3)) * 128
                   + (c & 15) * 8 + (s & 7)] = hv;
            }
        }
    } else {
        // ---- theta: unit = (d, 4 n) ----
        #pragma unroll
        for (int k = 0; k < 2; ++k) {
            int u = (t - 640) + k * 384;
            if (u < 512) {
                int d = u >> 5, n4 = u & 31;
                float acc0 = 0.f, acc1 = 0.f, acc2 = 0.f, acc3 = 0.f;
                for (int c = 0; c < 128; ++c) {
                    float wv = wt[d][c];
                    float4 xv = *(float4*)&xs[c][n4 * 4];
                    acc0 = fmaf(wv, xv.x, acc0); acc1 = fmaf(wv, xv.y, acc1);
                    acc2 = fmaf(wv, xv.z, acc2); acc3 = fmaf(wv, xv.w, acc3);
                }
                float bt = b_theta[d];
                const float LOG2E = 1.4426950408889634f;
                float tv[4] = { (acc0 + bt) * LOG2E, (acc1 + bt) * LOG2E,
                                (acc2 + bt) * LOG2E, (acc3 + bt) * LOG2E };
                #pragma unroll
                for (int j = 0; j < 4; ++j) {
                    int ng = h2 * 128 + n4 * 4 + j;        // global n
                    thA[(((size_t)b * 256 + (ng >> 4)) * 2 + (d >> 3)) * 128
                        + (ng & 15) * 8 + (d & 7)] = f2bf(tv[j]);
                }
            }
        }
    }
}

// ---------------------------------------------------------------------------
// K2: MFMA flash attention + final conv + residual.
// Block = 256 thr (4 waves), 64 n; each wave owns a 16-n Q-tile.
// Per superchunk (256 m): stage phi/g frags -> 16 score MFMAs (K 16->32 zero
// padded) -> one online-softmax rescale -> exp2 + packed bf16 P to LDS
// ([n][perm(m)], matching gB's permutation) -> 32 PV MFMAs.
// Epilogue: normalize, Obuf transpose via LDS, w_attn conv as 16 MFMAs.
// Verified layouts: C/D col=lane&15,row=quad*4+reg; A/B lane&15 + k=quad*8+j.
// ---------------------------------------------------------------------------
__global__ __launch_bounds__(256, 2) void k2_attn(
    const float* __restrict__ x,
    const unsigned short* __restrict__ thA,
    const unsigned short* __restrict__ phB,
    const unsigned short* __restrict__ gB,
    const float* __restrict__ w_attn, const float* __restrict__ b_attn,
    const float* __restrict__ sigma_p,
    float* __restrict__ out)
{
    __shared__ float smem[18816];                       // 75264 B
    unsigned short* phis = (unsigned short*)smem;       // 8192 B  [mt 16][qd 2][ml 16][dj 8]
    unsigned short* gs   = (unsigned short*)smem + 4096;// 32768 B [ch 8][cs 4][mq 4][cl 16][mj 8]
    char* Pall = (char*)smem + 40960;                   // 4 x 8448 B: P / Obuf per wave
    float* battn = (float*)((char*)smem + 74752);       // 512 B

    const int tid  = threadIdx.x;
    const int wave = tid >> 6;
    const int lane = tid & 63;
    const int q    = lane >> 4;         // quad 0..3
    const int l15  = lane & 15;
    const int b    = blockIdx.x & 7;    // XCD-local b
    const int n0   = (blockIdx.x >> 3) * 64;
    const int nw   = n0 + wave * 16;    // this wave's 16-n tile base
    char* Pbase = Pall + wave * 8448;   // [16 n][264 bf16] stride 528 B

    const float sg = sigma_p[0];

    // theta A-frag (quads 2,3 are the K zero-padding)
    short8 thf = {};
    if (q < 2)
        thf = *(const short8*)(thA + ((((size_t)b * 256 + (nw >> 4)) * 2 + q) * 16 + l15) * 8);

    floatx4 O[4];                        // O[cs] : D[n][c] accumulators
    #pragma unroll
    for (int cs = 0; cs < 4; ++cs) O[cs] = (floatx4){0.f, 0.f, 0.f, 0.f};
    float L[4]    = {0.f, 0.f, 0.f, 0.f};
    float rmax[4] = {-1e30f, -1e30f, -1e30f, -1e30f};

    for (int s = 0; s < 4; ++s) {
        __syncthreads();                 // previous PV done -> restage
        {   // stage phi (512 f4) + g (2048 f4) for this superchunk
            const float4* psrc = (const float4*)(phB + ((size_t)b * 64 + s * 16) * 256);
            const float4* gsrc = (const float4*)(gB + ((size_t)b * 32 + s * 8) * 2048);
            #pragma unroll
            for (int k = 0; k < 10; ++k) {
                int i = tid + k * 256;
                if (i < 512) ((float4*)smem)[i] = psrc[i];
                else ((float4*)((char*)smem + 8192))[i - 512] = gsrc[i - 512];
            }
        }
        __syncthreads();

        // ---- scores: 16 tiles of 16 m ----
        floatx4 S[16];
        #pragma unroll
        for (int mt = 0; mt < 16; ++mt) {
            short8 bf = {};
            if (q < 2) bf = *(const short8*)(phis + ((mt * 2 + q) * 16 + l15) * 8);
            S[mt] = __builtin_amdgcn_mfma_f32_16x16x32_bf16(
                        thf, bf, (floatx4){0.f, 0.f, 0.f, 0.f}, 0, 0, 0);
        }

        // ---- online softmax (scores already scaled by log2e -> use exp2) ----
        float cm[4];
        #pragma unroll
        for (int r = 0; r < 4; ++r) cm[r] = S[0][r];
        #pragma unroll
        for (int mt = 1; mt < 16; ++mt)
            #pragma unroll
            for (int r = 0; r < 4; ++r) cm[r] = fmaxf(cm[r], S[mt][r]);
        #pragma unroll
        for (int d = 1; d <= 8; d <<= 1)
            #pragma unroll
            for (int r = 0; r < 4; ++r) cm[r] = fmaxf(cm[r], __shfl_xor(cm[r], d, 64));
        float f[4];
        #pragma unroll
        for (int r = 0; r < 4; ++r) {
            float nm = fmaxf(rmax[r], cm[r]);
            f[r] = exp2f(rmax[r] - nm);
            rmax[r] = nm;
            L[r] *= f[r];
        }
        #pragma unroll
        for (int cs = 0; cs < 4; ++cs)
            #pragma unroll
            for (int r = 0; r < 4; ++r) O[cs][r] *= f[r];

        // exp2 + pack pairs (tile 2g2, 2g2+1) -> P[n][perm(m)] bf16
        #pragma unroll
        for (int g2 = 0; g2 < 8; ++g2) {
            #pragma unroll
            for (int r = 0; r < 4; ++r) {
                float pa = exp2f(S[2 * g2][r]     - rmax[r]);
                float pb = exp2f(S[2 * g2 + 1][r] - rmax[r]);
                L[r] += pa + pb;
                unsigned dw = (unsigned)f2bf(pa) | ((unsigned)f2bf(pb) << 16);
                *(unsigned*)(Pbase + (q * 4 + r) * 528 + g2 * 64 + l15 * 4) = dw;
            }
        }
        __syncthreads();                 // P visible (cross-lane within wave)

        // ---- PV: 8 chunks of 32 m ----
        #pragma unroll
        for (int ch = 0; ch < 8; ++ch) {
            short8 Af = *(const short8*)(Pbase + l15 * 528 + ch * 64 + q * 16);
            const unsigned short* gchunk = gs + ch * 2048;
            #pragma unroll
            for (int cs = 0; cs < 4; ++cs) {
                short8 Bf = *(const short8*)(gchunk + ((cs * 4 + q) * 16 + l15) * 8);
                O[cs] = __builtin_amdgcn_mfma_f32_16x16x32_bf16(Af, Bf, O[cs], 0, 0, 0);
            }
        }
    }

    // ---- epilogue ----
    __syncthreads();                     // flash loop done; gs region reusable
    {   // stage w_attn into A-frag layout [ot 8][kc 2][ol 16][c&31 32] (16 KB)
        unsigned short* wA = (unsigned short*)smem;
        #pragma unroll
        for (int k = 0; k < 8; ++k) {
            int i = tid + k * 256;               // 2048 f4 = 128x64 f32
            float4 wv = ((const float4*)w_attn)[i];
            int o = i >> 4, c4 = (i & 15) * 4;
            float vv[4] = {wv.x, wv.y, wv.z, wv.w};
            #pragma unroll
            for (int j = 0; j < 4; ++j) {
                int c = c4 + j;
                wA[((o >> 4) * 2 + (c >> 5)) * 512 + (o & 15) * 32 + (c & 31)] = f2bf(vv[j]);
            }
        }
        if (tid < 128) battn[tid] = b_attn[tid];
    }
    // normalize + write Obuf[n][c] bf16 (stride 72) into this wave's P region
    {
        float inv[4];
        #pragma unroll
        for (int r = 0; r < 4; ++r) inv[r] = 1.0f / L[r];
        unsigned short* Ob = (unsigned short*)Pbase;
        #pragma unroll
        for (int cs = 0; cs < 4; ++cs)
            #pragma unroll
            for (int r = 0; r < 4; ++r)
                Ob[(q * 4 + r) * 72 + cs * 16 + l15] = f2bf(O[cs][r] * inv[r]);
    }
    __syncthreads();                     // wA + Obuf visible

    {
        unsigned short* wA = (unsigned short*)smem;
        unsigned short* Ob = (unsigned short*)Pbase;
        short8 B0 = *(const short8*)(Ob + l15 * 72 + q * 8);        // c 0..31
        short8 B1 = *(const short8*)(Ob + l15 * 72 + 32 + q * 8);   // c 32..63
        const float* xw = x   + (size_t)b * Cn * Nn + nw + l15;
        float*       ow = out + (size_t)b * Cn * Nn + nw + l15;
        #pragma unroll
        for (int ot = 0; ot < 8; ++ot) {
            short8 A0 = *(const short8*)(wA + (ot * 2 + 0) * 512 + l15 * 32 + q * 8);
            short8 A1 = *(const short8*)(wA + (ot * 2 + 1) * 512 + l15 * 32 + q * 8);
            floatx4 D = __builtin_amdgcn_mfma_f32_16x16x32_bf16(
                            A0, B0, (floatx4){0.f, 0.f, 0.f, 0.f}, 0, 0, 0);
            D = __builtin_amdgcn_mfma_f32_16x16x32_bf16(A1, B1, D, 0, 0, 0);
            #pragma unroll
            for (int r = 0; r < 4; ++r) {
                int o = ot * 16 + q * 4 + r;
                float v = D[r] + battn[o];
                ow[(size_t)o * Nn] = xw[(size_t)o * Nn] + sg * v;
            }
        }
    }
}

extern "C" void kernel_launch(void* const* d_in, const int* in_sizes, int n_in,
                              void* d_out, int out_size, void* d_ws, size_t ws_size,
                              hipStream_t stream) {
    const float* x       = (const float*)d_in[0];
    const float* w_theta = (const float*)d_in[1];
    const float* b_theta = (const float*)d_in[2];
    const float* w_phi   = (const float*)d_in[3];
    const float* b_phi   = (const float*)d_in[4];
    const float* w_g     = (const float*)d_in[5];
    const float* b_g     = (const float*)d_in[6];
    const float* w_attn  = (const float*)d_in[7];
    const float* b_attn  = (const float*)d_in[8];
    const float* sigma   = (const float*)d_in[9];
    float* out = (float*)d_out;

    unsigned short* thA = (unsigned short*)d_ws;        // 524288 bf16 = 1 MB
    unsigned short* phB = thA + 524288;                 // 131072 bf16 = 256 KB
    unsigned short* gBp = phB + 131072;                 // 524288 bf16 = 1 MB

    k1_pre<<<256, 1024, 0, stream>>>(x, w_theta, b_theta, w_phi, b_phi,
                                     w_g, b_g, thA, phB, gBp);
    k2_attn<<<512, 256, 0, stream>>>(x, thA, phB, gBp, w_attn, b_attn, sigma, out);
}

// Round 4
// 117.073 us; speedup vs baseline: 2.7270x; 1.0339x over previous
//
#include <hip/hip_runtime.h>
#include <math.h>

#define Bn 8
#define Cn 128
#define Nn 4096   // H*W
#define Mn 1024   // N/4
#define C8n 16
#define C2n 64

typedef __attribute__((ext_vector_type(8))) short short8;            // 8 bf16 = 4 VGPRs
typedef __attribute__((ext_vector_type(4))) float floatx4;           // MFMA C/D
typedef __attribute__((ext_vector_type(4))) unsigned short ushortx4; // b64 pack

__device__ __forceinline__ unsigned short f2bf(float f) {
    union { float f; unsigned u; } v; v.f = f;
    unsigned r = v.u + 0x7fff + ((v.u >> 16) & 1);   // RNE
    return (unsigned short)(r >> 16);
}

// ---------------------------------------------------------------------------
// K1 (MFMA): per (b, h2) block computes theta (full res) and pooled phi/g for
// the 2-row strip via 16x16x32 bf16 MFMA. Output layouts are byte-identical
// to the round-3 kernel (k2 is unchanged):
//  thA[b][nt 256][qd 2][nl 16][dj 8]   (theta * log2e, A-frag order)
//  phB[b][mt 64][qd 2][ml 16][dj 8]    (phi, B-frag order)
//  gB [b][h2 32][cs 4][sq 4][cl 16][sj 8]  (g, B-frag, m permuted s=((m&15)<<1)|(m>>4))
// Frag layouts (verified m89/m91): A[row=l15][k=q*8+j], B[k=q*8+j][col=l15],
// C/D col=l15, row=q*4+r.
// ---------------------------------------------------------------------------
__global__ __launch_bounds__(256) void k1_pre(
    const float* __restrict__ x,
    const float* __restrict__ w_theta, const float* __restrict__ b_theta,
    const float* __restrict__ w_phi,   const float* __restrict__ b_phi,
    const float* __restrict__ w_g,     const float* __restrict__ b_g,
    unsigned short* __restrict__ thA,
    unsigned short* __restrict__ phB,
    unsigned short* __restrict__ gB)
{
    __shared__ unsigned short wA[6 * 4 * 64 * 8];   // 24 KB [ot][kc][lane][j]
    __shared__ unsigned short xB[8 * 4 * 64 * 8];   // 32 KB [pt][kc][lane][j]
    __shared__ unsigned short pool[80][33];         // 5.2 KB phi rows 0-15, g 16-79
    __shared__ float biases[96];                    // th*L2E 0-15, phi 16-31, g 32-95

    const int t    = threadIdx.x;
    const int b    = blockIdx.x & 7;
    const int h2   = blockIdx.x >> 3;
    const int wv   = t >> 6;
    const int lane = t & 63;
    const int q    = lane >> 4;
    const int l15  = lane & 15;
    const float L2E = 1.4426950408889634f;

    if (t < 96)
        biases[t] = (t < 16) ? b_theta[t] * L2E
                  : (t < 32) ? b_phi[t - 16] : b_g[t - 32];

    // ---- stage weights as bf16 A-frags: 96 oc x 32 float4 = 3072 units ----
    #pragma unroll
    for (int k = 0; k < 12; ++k) {
        int u  = t + k * 256;
        int oc = u >> 5, c4 = u & 31;
        const float* src = (oc < 16) ? (w_theta + oc * Cn)
                         : (oc < 32) ? (w_phi + (oc - 16) * Cn)
                                     : (w_g + (oc - 32) * Cn);
        float4 wv4 = *(const float4*)(src + c4 * 4);
        float sc = (oc < 16) ? L2E : 1.f;
        int c = c4 * 4;
        int ot = oc >> 4, kc = c >> 5, qq = (c >> 3) & 3, jj = c & 7;  // jj in {0,4}
        ushortx4 pk = { f2bf(wv4.x * sc), f2bf(wv4.y * sc),
                        f2bf(wv4.z * sc), f2bf(wv4.w * sc) };
        *(ushortx4*)(wA + (((ot * 4 + kc) * 64 + qq * 16 + (oc & 15)) * 8 + jj)) = pk;
    }

    // ---- stage x strip as bf16 B-frags: 32 c-quads x 128 pos = 4096 units ----
    const float* xb = x + (size_t)b * Cn * Nn + h2 * 128;
    #pragma unroll
    for (int k = 0; k < 16; ++k) {
        int u   = t + k * 256;
        int pos = u & 127, c4 = u >> 7;
        int c   = c4 * 4;
        float v0 = xb[(size_t)(c + 0) * Nn + pos];
        float v1 = xb[(size_t)(c + 1) * Nn + pos];
        float v2 = xb[(size_t)(c + 2) * Nn + pos];
        float v3 = xb[(size_t)(c + 3) * Nn + pos];
        int pt = pos >> 4, kc = c >> 5, qq = (c >> 3) & 3, jj = c & 7;
        ushortx4 pk = { f2bf(v0), f2bf(v1), f2bf(v2), f2bf(v3) };
        *(ushortx4*)(xB + (((pt * 4 + kc) * 64 + qq * 16 + (pos & 15)) * 8 + jj)) = pk;
    }
    __syncthreads();

    // ---- MFMA: wave wv owns pos-tiles {wv, wv+4} (same cols, rows 2h2/2h2+1)
    floatx4 acc[6][2];
    #pragma unroll
    for (int ot = 0; ot < 6; ++ot)
        #pragma unroll
        for (int p2 = 0; p2 < 2; ++p2) acc[ot][p2] = (floatx4){0.f, 0.f, 0.f, 0.f};

    #pragma unroll
    for (int kc = 0; kc < 4; ++kc) {
        short8 Bf0 = *(const short8*)(xB + ((wv * 4 + kc) * 64 + lane) * 8);
        short8 Bf1 = *(const short8*)(xB + (((wv + 4) * 4 + kc) * 64 + lane) * 8);
        #pragma unroll
        for (int ot = 0; ot < 6; ++ot) {
            short8 Af = *(const short8*)(wA + ((ot * 4 + kc) * 64 + lane) * 8);
            acc[ot][0] = __builtin_amdgcn_mfma_f32_16x16x32_bf16(Af, Bf0, acc[ot][0], 0, 0, 0);
            acc[ot][1] = __builtin_amdgcn_mfma_f32_16x16x32_bf16(Af, Bf1, acc[ot][1], 0, 0, 0);
        }
    }

    // ---- theta: bias + pack -> coalesced b64 global stores (no transpose) ----
    #pragma unroll
    for (int p2 = 0; p2 < 2; ++p2) {
        const int pt = wv + p2 * 4;
        ushortx4 pk;
        #pragma unroll
        for (int r = 0; r < 4; ++r)
            pk[r] = f2bf(acc[0][p2][r] + biases[q * 4 + r]);
        *(ushortx4*)(thA + ((((size_t)b * 256 + h2 * 8 + pt) * 2 + (q >> 1)) * 128
                            + l15 * 8 + (q & 1) * 4)) = pk;
    }

    // ---- phi/g: 2x2 maxpool in-register, +bias, park in LDS pool ----
    #pragma unroll
    for (int ot = 1; ot < 6; ++ot) {
        #pragma unroll
        for (int r = 0; r < 4; ++r) {
            float vmax = fmaxf(acc[ot][0][r], acc[ot][1][r]);
            float pmax = fmaxf(vmax, __shfl_xor(vmax, 1, 64));
            if ((l15 & 1) == 0) {
                int oc = (ot - 1) * 16 + q * 4 + r;      // 0..79
                int w2 = wv * 8 + (l15 >> 1);            // 0..31
                pool[oc][w2] = f2bf(pmax + biases[16 + oc]);
            }
        }
    }
    __syncthreads();

    // ---- pool -> global in k2's frag layouts (packed b128 stores) ----
    if (t < 64) {        // phi: units (w2h 2, ml 16, dh 2)
        int w2h = t >> 5, ml = (t >> 1) & 15, dh = t & 1;
        int w2 = w2h * 16 + ml;
        ushortx4 lo, hi;
        #pragma unroll
        for (int j = 0; j < 4; ++j) { lo[j] = pool[dh * 8 + j][w2];
                                      hi[j] = pool[dh * 8 + 4 + j][w2]; }
        unsigned short* dst = phB + (((size_t)b * 64 + h2 * 2 + w2h) * 2 + dh) * 128 + ml * 8;
        *(ushortx4*)dst = lo;
        *(ushortx4*)(dst + 4) = hi;
    }
    {                    // g: units (c 64, sq 4): w2 = (j&1)*16 + sq*4 + (j>>1)
        int c = t >> 2, sq = t & 3;
        ushortx4 lo, hi;
        #pragma unroll
        for (int j = 0; j < 8; ++j) {
            int w2 = (j & 1) * 16 + sq * 4 + (j >> 1);
            unsigned short v = pool[16 + c][w2];
            if (j < 4) lo[j] = v; else hi[j - 4] = v;
        }
        unsigned short* dst = gB + ((((size_t)b * 32 + h2) * 4 + (c >> 4)) * 4 + sq) * 128
                              + (c & 15) * 8;
        *(ushortx4*)dst = lo;
        *(ushortx4*)(dst + 4) = hi;
    }
}

// ---------------------------------------------------------------------------
// K2: MFMA flash attention + final conv + residual (unchanged from round 3).
// ---------------------------------------------------------------------------
__global__ __launch_bounds__(256, 2) void k2_attn(
    const float* __restrict__ x,
    const unsigned short* __restrict__ thA,
    const unsigned short* __restrict__ phB,
    const unsigned short* __restrict__ gB,
    const float* __restrict__ w_attn, const float* __restrict__ b_attn,
    const float* __restrict__ sigma_p,
    float* __restrict__ out)
{
    __shared__ float smem[18816];                       // 75264 B
    unsigned short* phis = (unsigned short*)smem;       // 8192 B  [mt 16][qd 2][ml 16][dj 8]
    unsigned short* gs   = (unsigned short*)smem + 4096;// 32768 B [ch 8][cs 4][mq 4][cl 16][mj 8]
    char* Pall = (char*)smem + 40960;                   // 4 x 8448 B: P / Obuf per wave
    float* battn = (float*)((char*)smem + 74752);       // 512 B

    const int tid  = threadIdx.x;
    const int wave = tid >> 6;
    const int lane = tid & 63;
    const int q    = lane >> 4;         // quad 0..3
    const int l15  = lane & 15;
    const int b    = blockIdx.x & 7;    // XCD-local b
    const int n0   = (blockIdx.x >> 3) * 64;
    const int nw   = n0 + wave * 16;    // this wave's 16-n tile base
    char* Pbase = Pall + wave * 8448;   // [16 n][264 bf16] stride 528 B

    const float sg = sigma_p[0];

    // theta A-frag (quads 2,3 are the K zero-padding)
    short8 thf = {};
    if (q < 2)
        thf = *(const short8*)(thA + ((((size_t)b * 256 + (nw >> 4)) * 2 + q) * 16 + l15) * 8);

    floatx4 O[4];                        // O[cs] : D[n][c] accumulators
    #pragma unroll
    for (int cs = 0; cs < 4; ++cs) O[cs] = (floatx4){0.f, 0.f, 0.f, 0.f};
    float L[4]    = {0.f, 0.f, 0.f, 0.f};
    float rmax[4] = {-1e30f, -1e30f, -1e30f, -1e30f};

    for (int s = 0; s < 4; ++s) {
        __syncthreads();                 // previous PV done -> restage
        {   // stage phi (512 f4) + g (2048 f4) for this superchunk
            const float4* psrc = (const float4*)(phB + ((size_t)b * 64 + s * 16) * 256);
            const float4* gsrc = (const float4*)(gB + ((size_t)b * 32 + s * 8) * 2048);
            #pragma unroll
            for (int k = 0; k < 10; ++k) {
                int i = tid + k * 256;
                if (i < 512) ((float4*)smem)[i] = psrc[i];
                else ((float4*)((char*)smem + 8192))[i - 512] = gsrc[i - 512];
            }
        }
        __syncthreads();

        // ---- scores: 16 tiles of 16 m ----
        floatx4 S[16];
        #pragma unroll
        for (int mt = 0; mt < 16; ++mt) {
            short8 bf = {};
            if (q < 2) bf = *(const short8*)(phis + ((mt * 2 + q) * 16 + l15) * 8);
            S[mt] = __builtin_amdgcn_mfma_f32_16x16x32_bf16(
                        thf, bf, (floatx4){0.f, 0.f, 0.f, 0.f}, 0, 0, 0);
        }

        // ---- online softmax (scores already scaled by log2e -> use exp2) ----
        float cm[4];
        #pragma unroll
        for (int r = 0; r < 4; ++r) cm[r] = S[0][r];
        #pragma unroll
        for (int mt = 1; mt < 16; ++mt)
            #pragma unroll
            for (int r = 0; r < 4; ++r) cm[r] = fmaxf(cm[r], S[mt][r]);
        #pragma unroll
        for (int d = 1; d <= 8; d <<= 1)
            #pragma unroll
            for (int r = 0; r < 4; ++r) cm[r] = fmaxf(cm[r], __shfl_xor(cm[r], d, 64));
        float f[4];
        #pragma unroll
        for (int r = 0; r < 4; ++r) {
            float nm = fmaxf(rmax[r], cm[r]);
            f[r] = exp2f(rmax[r] - nm);
            rmax[r] = nm;
            L[r] *= f[r];
        }
        #pragma unroll
        for (int cs = 0; cs < 4; ++cs)
            #pragma unroll
            for (int r = 0; r < 4; ++r) O[cs][r] *= f[r];

        // exp2 + pack pairs (tile 2g2, 2g2+1) -> P[n][perm(m)] bf16
        #pragma unroll
        for (int g2 = 0; g2 < 8; ++g2) {
            #pragma unroll
            for (int r = 0; r < 4; ++r) {
                float pa = exp2f(S[2 * g2][r]     - rmax[r]);
                float pb = exp2f(S[2 * g2 + 1][r] - rmax[r]);
                L[r] += pa + pb;
                unsigned dw = (unsigned)f2bf(pa) | ((unsigned)f2bf(pb) << 16);
                *(unsigned*)(Pbase + (q * 4 + r) * 528 + g2 * 64 + l15 * 4) = dw;
            }
        }
        __syncthreads();                 // P visible

        // ---- PV: 8 chunks of 32 m ----
        #pragma unroll
        for (int ch = 0; ch < 8; ++ch) {
            short8 Af = *(const short8*)(Pbase + l15 * 528 + ch * 64 + q * 16);
            const unsigned short* gchunk = gs + ch * 2048;
            #pragma unroll
            for (int cs = 0; cs < 4; ++cs) {
                short8 Bf = *(const short8*)(gchunk + ((cs * 4 + q) * 16 + l15) * 8);
                O[cs] = __builtin_amdgcn_mfma_f32_16x16x32_bf16(Af, Bf, O[cs], 0, 0, 0);
            }
        }
    }

    // ---- epilogue ----
    __syncthreads();                     // flash loop done; gs region reusable
    {   // stage w_attn into A-frag layout [ot 8][kc 2][ol 16][c&31 32] (16 KB)
        unsigned short* wAe = (unsigned short*)smem;
        #pragma unroll
        for (int k = 0; k < 8; ++k) {
            int i = tid + k * 256;               // 2048 f4 = 128x64 f32
            float4 wv = ((const float4*)w_attn)[i];
            int o = i >> 4, c4 = (i & 15) * 4;
            float vv[4] = {wv.x, wv.y, wv.z, wv.w};
            #pragma unroll
            for (int j = 0; j < 4; ++j) {
                int c = c4 + j;
                wAe[((o >> 4) * 2 + (c >> 5)) * 512 + (o & 15) * 32 + (c & 31)] = f2bf(vv[j]);
            }
        }
        if (tid < 128) battn[tid] = b_attn[tid];
    }
    // normalize + write Obuf[n][c] bf16 (stride 72) into this wave's P region
    {
        float inv[4];
        #pragma unroll
        for (int r = 0; r < 4; ++r) inv[r] = 1.0f / L[r];
        unsigned short* Ob = (unsigned short*)Pbase;
        #pragma unroll
        for (int cs = 0; cs < 4; ++cs)
            #pragma unroll
            for (int r = 0; r < 4; ++r)
                Ob[(q * 4 + r) * 72 + cs * 16 + l15] = f2bf(O[cs][r] * inv[r]);
    }
    __syncthreads();                     // wAe + Obuf visible

    {
        unsigned short* wAe = (unsigned short*)smem;
        unsigned short* Ob = (unsigned short*)Pbase;
        short8 B0 = *(const short8*)(Ob + l15 * 72 + q * 8);        // c 0..31
        short8 B1 = *(const short8*)(Ob + l15 * 72 + 32 + q * 8);   // c 32..63
        const float* xw = x   + (size_t)b * Cn * Nn + nw + l15;
        float*       ow = out + (size_t)b * Cn * Nn + nw + l15;
        #pragma unroll
        for (int ot = 0; ot < 8; ++ot) {
            short8 A0 = *(const short8*)(wAe + (ot * 2 + 0) * 512 + l15 * 32 + q * 8);
            short8 A1 = *(const short8*)(wAe + (ot * 2 + 1) * 512 + l15 * 32 + q * 8);
            floatx4 D = __builtin_amdgcn_mfma_f32_16x16x32_bf16(
                            A0, B0, (floatx4){0.f, 0.f, 0.f, 0.f}, 0, 0, 0);
            D = __builtin_amdgcn_mfma_f32_16x16x32_bf16(A1, B1, D, 0, 0, 0);
            #pragma unroll
            for (int r = 0; r < 4; ++r) {
                int o = ot * 16 + q * 4 + r;
                float v = D[r] + battn[o];
                ow[(size_t)o * Nn] = xw[(size_t)o * Nn] + sg * v;
            }
        }
    }
}

extern "C" void kernel_launch(void* const* d_in, const int* in_sizes, int n_in,
                              void* d_out, int out_size, void* d_ws, size_t ws_size,
                              hipStream_t stream) {
    const float* x       = (const float*)d_in[0];
    const float* w_theta = (const float*)d_in[1];
    const float* b_theta = (const float*)d_in[2];
    const float* w_phi   = (const float*)d_in[3];
    const float* b_phi   = (const float*)d_in[4];
    const float* w_g     = (const float*)d_in[5];
    const float* b_g     = (const float*)d_in[6];
    const float* w_attn  = (const float*)d_in[7];
    const float* b_attn  = (const float*)d_in[8];
    const float* sigma   = (const float*)d_in[9];
    float* out = (float*)d_out;

    unsigned short* thA = (unsigned short*)d_ws;        // 524288 bf16 = 1 MB
    unsigned short* phB = thA + 524288;                 // 131072 bf16 = 256 KB
    unsigned short* gBp = phB + 131072;                 // 524288 bf16 = 1 MB

    k1_pre<<<256, 256, 0, stream>>>(x, w_theta, b_theta, w_phi, b_phi,
                                    w_g, b_g, thA, phB, gBp);
    k2_attn<<<512, 256, 0, stream>>>(x, thA, phB, gBp, w_attn, b_attn, sigma, out);
}